// Round 3
// baseline (275.881 us; speedup 1.0000x reference)
//
#include <hip/hip_runtime.h>

#define IN_F 4096
#define OUT_F 11008
#define BATCH 64
#define NT (OUT_F / 16)      // 688 n-tiles of 16 output rows
#define NSTEP (IN_F / 64)    // 64 K-steps of 64
#define KS 8                 // K-split in gemm
#define SPW (NSTEP / KS)     // 8 steps per gemm block

typedef int v4i __attribute__((ext_vector_type(4)));
typedef float v4f __attribute__((ext_vector_type(4)));
typedef signed char i8;

// ws layout (bytes)
#define WS_XQ 0u                          // 256 KB: x quantized, A-fragment order
#define WS_XS (256u * 1024u)              // 1 KB: x per-row scales
#define WS_WB (257u * 1024u)              // 45 MB: weights i8, B-fragment order
#define WS_PART (WS_WB + (size_t)OUT_F * IN_F)  // 22.5 MB: K-split partials

__device__ __forceinline__ int pack4(int a0, int a1, int a2, int a3) {
    return (a0 & 0xff) | ((a1 & 0xff) << 8) | ((a2 & 0xff) << 16) |
           ((unsigned)a3 << 24);
}

// ---------------------------------------------------------------------------
// quant_x: dynamic per-row int8 quantization of x, scattered into MFMA
// A-fragment order (proven in R2): A[m=lane&15][k=(lane>>4)*16+j]
// xq byte ((s*256 + mt*64 + lane)*16 + j) = q(x[mt*16+(lane&15)][s*64+(lane>>4)*16+j])
// ---------------------------------------------------------------------------
__global__ __launch_bounds__(256)
void quant_x_kernel(const float* __restrict__ x, i8* __restrict__ xq,
                    float* __restrict__ xscale)
{
    const int b = blockIdx.x;
    const int t = threadIdx.x;
    const float* xr = x + (size_t)b * IN_F;
    const int i0 = t * 16;

    float vals[16];
    float m = 0.0f;
#pragma unroll
    for (int j = 0; j < 16; ++j) {
        vals[j] = xr[i0 + j];
        m = fmaxf(m, fabsf(vals[j]));
    }

    __shared__ float red[256];
    red[t] = m;
    __syncthreads();
    for (int s = 128; s > 0; s >>= 1) {
        if (t < s) red[t] = fmaxf(red[t], red[t + s]);
        __syncthreads();
    }
    const float amax = red[0];
    const float inv = (amax > 0.0f) ? (127.0f / amax) : 0.0f;
    if (t == 0) xscale[b] = (amax > 0.0f) ? (amax / 127.0f) : 1.0f;

    const int kc   = i0 >> 6;
    const int quad = (i0 >> 4) & 3;
    const int mt   = b >> 4;
    const int lane = (b & 15) | (quad << 4);

    i8 q[16];
#pragma unroll
    for (int j = 0; j < 16; ++j) {
        float r = rintf(vals[j] * inv);
        r = fminf(127.0f, fmaxf(-127.0f, r));
        q[j] = (i8)(int)r;
    }
    *(v4i*)(xq + ((size_t)(kc * 256 + mt * 64 + lane) * 16)) = *(const v4i*)q;
}

// ---------------------------------------------------------------------------
// pack_w: int32 weights -> i8 in exact B-fragment lane order.
// Block = (sg, nt): 16 rows x 256 k-int32. Reads: instr r covers rows' int32s
// [r*64+c*4 .. +3] -> per wave 4 contiguous 1KB row-runs (16 fully-used lines).
// LDS [4 r][16 row][16 c] pad 17 transposes to fragment order.
// wb byte ((nt*64 + s)*64 + (n|q<<4))*16 + j = (i8)W[nt*16+n][s*64+q*16+j]
// ---------------------------------------------------------------------------
__global__ __launch_bounds__(256)
void pack_w_kernel(const int* __restrict__ wq, i8* __restrict__ wb)
{
    const int nt = blockIdx.y;
    const int sg = blockIdx.x;     // group of 4 K-steps
    const int t  = threadIdx.x;
    const int row = t >> 4;        // 0..15
    const int c   = t & 15;        // k-quad within a 64-int32 step

    __shared__ int lds[4 * 272];   // [r]*272 + row*17 + c

    const int* base = wq + (size_t)(nt * 16 + row) * IN_F + sg * 256 + c * 4;
#pragma unroll
    for (int r = 0; r < 4; ++r) {
        v4i w = *(const v4i*)(base + r * 64);
        lds[r * 272 + row * 17 + c] = pack4(w[0], w[1], w[2], w[3]);
    }
    __syncthreads();

    const int sl = t >> 6;         // local step 0..3
    const int L  = t & 63;         // fragment lane
    const int n  = t & 15;
    const int q  = (t >> 4) & 3;
    v4i o;
#pragma unroll
    for (int d = 0; d < 4; ++d)
        o[d] = lds[sl * 272 + n * 17 + q * 4 + d];
    *(v4i*)(wb + ((size_t)(nt * 64 + sg * 4 + sl) * 64 + L) * 16) = o;
}

// ---------------------------------------------------------------------------
// gemm: wave w owns n-tile bx*4+w, K-chunk by (8 steps). B-fragment = ONE
// lane-contiguous v4i per step (wave reads 1KB contiguous). A from L2-hot xq.
// 4 MFMA/step (4 m-tiles). No LDS, no barriers, no atomics: scaled partials
// stored disjointly to ws.
// ---------------------------------------------------------------------------
__global__ __launch_bounds__(256)
void gemm_kernel(const i8* __restrict__ wb, const i8* __restrict__ xq,
                 const float* __restrict__ xscale,
                 const float* __restrict__ wscale,
                 float* __restrict__ part)
{
    const int lane = threadIdx.x & 63;
    const int wave = threadIdx.x >> 6;
    const int nt   = blockIdx.x * 4 + wave;
    const int ks   = blockIdx.y;

    const v4i* pB = (const v4i*)wb + ((size_t)nt * 64 + ks * SPW) * 64 + lane;
    const v4i* pA = (const v4i*)xq + (size_t)(ks * SPW) * 256 + lane;

    v4i acc[4];
#pragma unroll
    for (int mt = 0; mt < 4; ++mt) acc[mt] = (v4i){0, 0, 0, 0};

    v4i bC, bN, aC[4], aN[4];
    bC = pB[0];
#pragma unroll
    for (int mt = 0; mt < 4; ++mt) aC[mt] = pA[mt * 64];

#pragma unroll
    for (int ss = 0; ss < SPW; ++ss) {
        if (ss + 1 < SPW) {
            bN = pB[(size_t)(ss + 1) * 64];
#pragma unroll
            for (int mt = 0; mt < 4; ++mt) aN[mt] = pA[(size_t)(ss + 1) * 256 + mt * 64];
        }
#pragma unroll
        for (int mt = 0; mt < 4; ++mt)
            acc[mt] = __builtin_amdgcn_mfma_i32_16x16x64_i8(aC[mt], bC, acc[mt], 0, 0, 0);
        if (ss + 1 < SPW) {
            bC = bN;
#pragma unroll
            for (int mt = 0; mt < 4; ++mt) aC[mt] = aN[mt];
        }
    }

    // C/D: col = lane&15 (n), row = (lane>>4)*4 + r (batch). Scale here, sum later.
    const int n = lane & 15;
    const int o = nt * 16 + n;
    const float wsc = wscale[o];
    const int rbase = (lane >> 4) * 4;
    float* pp = part + (size_t)ks * BATCH * OUT_F + o;
#pragma unroll
    for (int mt = 0; mt < 4; ++mt) {
#pragma unroll
        for (int r = 0; r < 4; ++r) {
            const int brow = mt * 16 + rbase + r;
            pp[(size_t)brow * OUT_F] = (float)acc[mt][r] * xscale[brow] * wsc;
        }
    }
}

// ---------------------------------------------------------------------------
// reduce: out = bias + sum over KS partials. float4-vectorized, exact-cover.
// ---------------------------------------------------------------------------
__global__ __launch_bounds__(256)
void reduce_kernel(const float* __restrict__ part, const float* __restrict__ bias,
                   float* __restrict__ out)
{
    const int i = (blockIdx.x * 256 + threadIdx.x) * 4;   // grid covers BATCH*OUT_F exactly
    const int o = i % OUT_F;
    v4f s = *(const v4f*)(bias + o);
#pragma unroll
    for (int ks = 0; ks < KS; ++ks)
        s += *(const v4f*)(part + (size_t)ks * BATCH * OUT_F + i);
    *(v4f*)(out + i) = s;
}

extern "C" void kernel_launch(void* const* d_in, const int* in_sizes, int n_in,
                              void* d_out, int out_size, void* d_ws, size_t ws_size,
                              hipStream_t stream)
{
    const float* x      = (const float*)d_in[0];
    const int*   wq     = (const int*)d_in[1];   // integer inputs arrive as int32
    const float* wscale = (const float*)d_in[2];
    const float* bias   = (const float*)d_in[3];
    float* out = (float*)d_out;

    i8*    xq     = (i8*)d_ws + WS_XQ;
    float* xscale = (float*)((char*)d_ws + WS_XS);
    i8*    wb     = (i8*)d_ws + WS_WB;
    float* partials = (float*)((char*)d_ws + WS_PART);

    quant_x_kernel<<<BATCH, 256, 0, stream>>>(x, xq, xscale);
    pack_w_kernel<<<dim3(16, NT), 256, 0, stream>>>(wq, wb);
    gemm_kernel<<<dim3(NT / 4, KS), 256, 0, stream>>>(wb, xq, xscale, wscale, partials);
    reduce_kernel<<<(BATCH * OUT_F) / 1024, 256, 0, stream>>>(partials, bias, out);
}

// Round 4
// 267.706 us; speedup vs baseline: 1.0305x; 1.0305x over previous
//
#include <hip/hip_runtime.h>

#define IN_F 4096
#define OUT_F 11008
#define BATCH 64
#define NT (OUT_F / 16)        // 688 n-tiles / blocks
#define SPW 16                 // K-steps per wave (64 steps / 4 waves)

typedef int v4i __attribute__((ext_vector_type(4)));
typedef signed char i8;

__device__ __forceinline__ int pack4(int a0, int a1, int a2, int a3) {
    return (a0 & 0xff) | ((a1 & 0xff) << 8) | ((a2 & 0xff) << 16) |
           ((unsigned)a3 << 24);
}

// ---------------------------------------------------------------------------
// quant_x (proven R2/R3): per-row int8 quantization of x into MFMA A-fragment
// order: xq v4i index (s*256 + mt*64 + lane) = A-frag(step s, m-tile mt, lane)
// where A[m=lane&15][k=(lane>>4)*16+j].
// ---------------------------------------------------------------------------
__global__ __launch_bounds__(256)
void quant_x_kernel(const float* __restrict__ x, i8* __restrict__ xq,
                    float* __restrict__ xscale)
{
    const int b = blockIdx.x;
    const int t = threadIdx.x;
    const float* xr = x + (size_t)b * IN_F;
    const int i0 = t * 16;

    float vals[16];
    float m = 0.0f;
#pragma unroll
    for (int j = 0; j < 16; ++j) {
        vals[j] = xr[i0 + j];
        m = fmaxf(m, fabsf(vals[j]));
    }

    __shared__ float red[256];
    red[t] = m;
    __syncthreads();
    for (int s = 128; s > 0; s >>= 1) {
        if (t < s) red[t] = fmaxf(red[t], red[t + s]);
        __syncthreads();
    }
    const float amax = red[0];
    const float inv = (amax > 0.0f) ? (127.0f / amax) : 0.0f;
    if (t == 0) xscale[b] = (amax > 0.0f) ? (amax / 127.0f) : 1.0f;

    const int kc   = i0 >> 6;
    const int quad = (i0 >> 4) & 3;
    const int mt   = b >> 4;
    const int lane = (b & 15) | (quad << 4);

    i8 q[16];
#pragma unroll
    for (int j = 0; j < 16; ++j) {
        float r = rintf(vals[j] * inv);
        r = fminf(127.0f, fmaxf(-127.0f, r));
        q[j] = (i8)(int)r;
    }
    *(v4i*)(xq + ((size_t)(kc * 256 + mt * 64 + lane) * 16)) = *(const v4i*)q;
}

// ---------------------------------------------------------------------------
// Single-pass GEMM. Block = n-tile (16 output rows); its 4 waves split K in
// quarters (16 steps of 64 weights each). Per wave-step:
//   - 4 perfectly-coalesced dwordx4 loads (4 rows x 256 B fully-consumed runs)
//   - transpose via private padded LDS tile (stride 68 dwords: both phases
//     hit every bank exactly 8x = conflict-free minimum)
//   - pack int32->i8 in-register, 4x mfma_i32_16x16x64_i8 (exact int32 acc)
// Cross-wave int combine in LDS, single direct store with bias: no init, no
// partials, no reduce, no atomics. HBM: 180 MB weights + 2.8 MB out.
// ---------------------------------------------------------------------------
__global__ __launch_bounds__(256)
void gemm_kernel(const int* __restrict__ wq, const i8* __restrict__ xq,
                 const float* __restrict__ xscale,
                 const float* __restrict__ wscale,
                 const float* __restrict__ bias,
                 float* __restrict__ out)
{
    __shared__ int lds[4 * 1088];   // per-wave 1088-dword region (16 rows x 68)
    const int lane = threadIdx.x & 63;
    const int wave = threadIdx.x >> 6;
    const int nt   = blockIdx.x;
    int* wlds = lds + wave * 1088;

    const int n    = lane & 15;     // B-fragment n / output row within tile
    const int q    = lane >> 4;     // B-fragment k-quad
    const int grow = lane >> 4;     // row-in-group for coalesced loads
    const int gcol = (lane & 15) * 4;

    const int s0 = wave * SPW;      // this wave's first K-step
    const int* wbase = wq + (size_t)(nt * 16) * IN_F + s0 * 64 + gcol;
    const v4i* pA = (const v4i*)xq + (size_t)s0 * 256 + lane;

    v4i acc[4];
#pragma unroll
    for (int mt = 0; mt < 4; ++mt) acc[mt] = (v4i){0, 0, 0, 0};

    v4i wC[4], wN[4], aC[4], aN[4];
    // prologue: step s0
#pragma unroll
    for (int p = 0; p < 4; ++p)
        wC[p] = *(const v4i*)(wbase + (size_t)(4 * p + grow) * IN_F);
#pragma unroll
    for (int mt = 0; mt < 4; ++mt) aC[mt] = pA[mt * 64];

    for (int ss = 0; ss < SPW; ++ss) {
        if (ss + 1 < SPW) {
            const int* nb = wbase + (ss + 1) * 64;
#pragma unroll
            for (int p = 0; p < 4; ++p)
                wN[p] = *(const v4i*)(nb + (size_t)(4 * p + grow) * IN_F);
#pragma unroll
            for (int mt = 0; mt < 4; ++mt)
                aN[mt] = pA[(ss + 1) * 256 + mt * 64];
        }
        // transpose current step through this wave's LDS tile
#pragma unroll
        for (int p = 0; p < 4; ++p)
            *(v4i*)(wlds + (4 * p + grow) * 68 + gcol) = wC[p];
        asm volatile("s_waitcnt lgkmcnt(0)" ::: "memory");
        v4i rd[4];
#pragma unroll
        for (int d = 0; d < 4; ++d)
            rd[d] = *(const v4i*)(wlds + n * 68 + q * 16 + 4 * d);
        asm volatile("s_waitcnt lgkmcnt(0)" ::: "memory");

        v4i bfrag;
#pragma unroll
        for (int d = 0; d < 4; ++d)
            bfrag[d] = pack4(rd[d][0], rd[d][1], rd[d][2], rd[d][3]);

#pragma unroll
        for (int mt = 0; mt < 4; ++mt)
            acc[mt] = __builtin_amdgcn_mfma_i32_16x16x64_i8(aC[mt], bfrag, acc[mt], 0, 0, 0);

        if (ss + 1 < SPW) {
#pragma unroll
            for (int p = 0; p < 4; ++p) wC[p] = wN[p];
#pragma unroll
            for (int mt = 0; mt < 4; ++mt) aC[mt] = aN[mt];
        }
    }

    // cross-wave combine: each wave drops its int acc into its own LDS region
    // (stride 17 -> conflict-free b32), then one barrier, then direct store.
#pragma unroll
    for (int mt = 0; mt < 4; ++mt)
#pragma unroll
        for (int r = 0; r < 4; ++r)
            wlds[lane * 17 + mt * 4 + r] = acc[mt][r];
    __syncthreads();

    const int mt2 = wave;            // wave id doubles as m-tile in epilogue
    const int o = nt * 16 + n;
    const float wsc = wscale[o];
    const float bo  = bias[o];
#pragma unroll
    for (int r = 0; r < 4; ++r) {
        int s = 0;
#pragma unroll
        for (int w = 0; w < 4; ++w)
            s += lds[w * 1088 + lane * 17 + mt2 * 4 + r];
        const int b = mt2 * 16 + q * 4 + r;   // C/D: row = quad*4 + reg
        out[(size_t)b * OUT_F + o] = (float)s * xscale[b] * wsc + bo;
    }
}

extern "C" void kernel_launch(void* const* d_in, const int* in_sizes, int n_in,
                              void* d_out, int out_size, void* d_ws, size_t ws_size,
                              hipStream_t stream)
{
    const float* x      = (const float*)d_in[0];
    const int*   wq     = (const int*)d_in[1];   // integer inputs arrive as int32
    const float* wscale = (const float*)d_in[2];
    const float* bias   = (const float*)d_in[3];
    float* out = (float*)d_out;

    i8*    xq     = (i8*)d_ws;
    float* xscale = (float*)((char*)d_ws + 256u * 1024u);

    quant_x_kernel<<<BATCH, 256, 0, stream>>>(x, xq, xscale);
    gemm_kernel<<<NT, 256, 0, stream>>>(wq, xq, xscale, wscale, bias, out);
}

// Round 5
// 261.706 us; speedup vs baseline: 1.0542x; 1.0229x over previous
//
#include <hip/hip_runtime.h>

#define IN_F 4096
#define OUT_F 11008
#define BATCH 64
#define NT (OUT_F / 16)        // 688 n-tiles / blocks
#define NWAVE 8                // waves per block
#define SPW (IN_F / 64 / NWAVE)  // 8 K-steps of 64 per wave

typedef int v4i __attribute__((ext_vector_type(4)));
typedef signed char i8;

__device__ __forceinline__ int pack4(int a0, int a1, int a2, int a3) {
    return (a0 & 0xff) | ((a1 & 0xff) << 8) | ((a2 & 0xff) << 16) |
           ((unsigned)a3 << 24);
}

// ---------------------------------------------------------------------------
// quant_x (proven R2-R4): per-row int8 quantization of x into MFMA A-fragment
// order: xq v4i index (s*256 + mt*64 + lane) = A-frag(step s, m-tile mt, lane),
// A[m=lane&15][k=(lane>>4)*16+j].
// ---------------------------------------------------------------------------
__global__ __launch_bounds__(256)
void quant_x_kernel(const float* __restrict__ x, i8* __restrict__ xq,
                    float* __restrict__ xscale)
{
    const int b = blockIdx.x;
    const int t = threadIdx.x;
    const float* xr = x + (size_t)b * IN_F;
    const int i0 = t * 16;

    float vals[16];
    float m = 0.0f;
#pragma unroll
    for (int j = 0; j < 16; ++j) {
        vals[j] = xr[i0 + j];
        m = fmaxf(m, fabsf(vals[j]));
    }

    __shared__ float red[256];
    red[t] = m;
    __syncthreads();
    for (int s = 128; s > 0; s >>= 1) {
        if (t < s) red[t] = fmaxf(red[t], red[t + s]);
        __syncthreads();
    }
    const float amax = red[0];
    const float inv = (amax > 0.0f) ? (127.0f / amax) : 0.0f;
    if (t == 0) xscale[b] = (amax > 0.0f) ? (amax / 127.0f) : 1.0f;

    const int kc   = i0 >> 6;
    const int quad = (i0 >> 4) & 3;
    const int mt   = b >> 4;
    const int lane = (b & 15) | (quad << 4);

    i8 q[16];
#pragma unroll
    for (int j = 0; j < 16; ++j) {
        float r = rintf(vals[j] * inv);
        r = fminf(127.0f, fmaxf(-127.0f, r));
        q[j] = (i8)(int)r;
    }
    *(v4i*)(xq + ((size_t)(kc * 256 + mt * 64 + lane) * 16)) = *(const v4i*)q;
}

// ---------------------------------------------------------------------------
// Single-pass GEMM, 8 waves/block. Block = n-tile (16 output rows); waves
// split K into eighths (8 steps of 64). Per wave-step:
//   - 4 perfectly-coalesced dwordx4 loads (4 x 256B fully-consumed row runs)
//   - transpose via wave-private padded LDS tile (16 x 68 dwords; both phases
//     at the wave64 8-hits/bank minimum)
//   - pack int32->i8, 4x mfma_i32_16x16x64_i8 (exact int32 accumulate)
// 1-step register prefetch; compiler-scheduled waitcnts (no forced drains).
// Cross-wave int combine in LDS, single direct store with bias.
// HBM: 180 MB weights + 1 MB xq + 2.8 MB out.
// ---------------------------------------------------------------------------
__global__ __launch_bounds__(512)
void gemm_kernel(const int* __restrict__ wq, const i8* __restrict__ xq,
                 const float* __restrict__ xscale,
                 const float* __restrict__ wscale,
                 const float* __restrict__ bias,
                 float* __restrict__ out)
{
    __shared__ int lds[NWAVE * 1088];   // per-wave 1088-dword region (16 x 68)
    const int lane = threadIdx.x & 63;
    const int wave = threadIdx.x >> 6;
    const int nt   = blockIdx.x;
    int* wlds = lds + wave * 1088;

    const int n    = lane & 15;     // B-fragment n / output col-in-tile
    const int q    = lane >> 4;     // B-fragment k-quad
    const int grow = lane >> 4;     // row-in-group for coalesced loads
    const int gcol = (lane & 15) * 4;

    const int s0 = wave * SPW;      // this wave's first K-step
    const int* wbase = wq + (size_t)(nt * 16) * IN_F + s0 * 64 + gcol;
    const v4i* pA = (const v4i*)xq + (size_t)s0 * 256 + lane;

    v4i acc[4];
#pragma unroll
    for (int mt = 0; mt < 4; ++mt) acc[mt] = (v4i){0, 0, 0, 0};

    v4i wC[4], wN[4], aC[4], aN[4];
    // prologue: step s0
#pragma unroll
    for (int p = 0; p < 4; ++p)
        wC[p] = *(const v4i*)(wbase + (size_t)(4 * p + grow) * IN_F);
#pragma unroll
    for (int mt = 0; mt < 4; ++mt) aC[mt] = pA[mt * 64];

#pragma unroll
    for (int ss = 0; ss < SPW; ++ss) {
        if (ss + 1 < SPW) {
            const int* nb = wbase + (ss + 1) * 64;
#pragma unroll
            for (int p = 0; p < 4; ++p)
                wN[p] = *(const v4i*)(nb + (size_t)(4 * p + grow) * IN_F);
#pragma unroll
            for (int mt = 0; mt < 4; ++mt)
                aN[mt] = pA[(ss + 1) * 256 + mt * 64];
        }
        // transpose current step through this wave's private LDS tile
#pragma unroll
        for (int p = 0; p < 4; ++p)
            *(v4i*)(wlds + (4 * p + grow) * 68 + gcol) = wC[p];
        v4i rd[4];
#pragma unroll
        for (int d = 0; d < 4; ++d)
            rd[d] = *(const v4i*)(wlds + n * 68 + q * 16 + 4 * d);

        v4i bfrag;
#pragma unroll
        for (int d = 0; d < 4; ++d)
            bfrag[d] = pack4(rd[d][0], rd[d][1], rd[d][2], rd[d][3]);

#pragma unroll
        for (int mt = 0; mt < 4; ++mt)
            acc[mt] = __builtin_amdgcn_mfma_i32_16x16x64_i8(aC[mt], bfrag, acc[mt], 0, 0, 0);

        if (ss + 1 < SPW) {
#pragma unroll
            for (int p = 0; p < 4; ++p) wC[p] = wN[p];
#pragma unroll
            for (int mt = 0; mt < 4; ++mt) aC[mt] = aN[mt];
        }
    }

    // cross-wave combine: each wave drops its int acc into its own LDS region
    // (stride 17: odd -> every bank 2x = free), one barrier, direct store.
#pragma unroll
    for (int mt = 0; mt < 4; ++mt)
#pragma unroll
        for (int r = 0; r < 4; ++r)
            wlds[lane * 17 + mt * 4 + r] = acc[mt][r];
    __syncthreads();

    // 512 threads -> 1024 outputs: wave pair (mt2, rp) x lane (n, q) x 2 rows
    const int mt2 = wave >> 1;
    const int rp  = (wave & 1) * 2;
    const int o   = nt * 16 + n;
    const float wsc = wscale[o];
    const float bo  = bias[o];
#pragma unroll
    for (int j = 0; j < 2; ++j) {
        const int r = rp + j;
        int s = 0;
#pragma unroll
        for (int w = 0; w < NWAVE; ++w)
            s += lds[w * 1088 + lane * 17 + mt2 * 4 + r];
        const int b = mt2 * 16 + q * 4 + r;   // C/D: row = quad*4 + reg
        out[(size_t)b * OUT_F + o] = (float)s * xscale[b] * wsc + bo;
    }
}

extern "C" void kernel_launch(void* const* d_in, const int* in_sizes, int n_in,
                              void* d_out, int out_size, void* d_ws, size_t ws_size,
                              hipStream_t stream)
{
    const float* x      = (const float*)d_in[0];
    const int*   wq     = (const int*)d_in[1];   // integer inputs arrive as int32
    const float* wscale = (const float*)d_in[2];
    const float* bias   = (const float*)d_in[3];
    float* out = (float*)d_out;

    i8*    xq     = (i8*)d_ws;
    float* xscale = (float*)((char*)d_ws + 256u * 1024u);

    quant_x_kernel<<<BATCH, 256, 0, stream>>>(x, xq, xscale);
    gemm_kernel<<<NT, 512, 0, stream>>>(wq, xq, xscale, wscale, bias, out);
}